// Round 6
// baseline (54022.650 us; speedup 1.0000x reference)
//
#include <hip/hip_runtime.h>

#define Bn 4096
#define Tn 256
#define NZ 64
#define Hn 512
#define INn 68
#define DPRv 24.0f
#define MB 32
#define NWAVE 8
#define NTHREADS 512
#define NBLK 128

// unified per-wave weight stream: 37 groups (32 h + 5 ext) x 10 frags x 64 lanes x 8 shorts
#define NGRP 37
#define GRP_SHORTS (10 * 64 * 8)            /* 5120 */
#define WAVE_SHORTS (NGRP * GRP_SHORTS)     /* 189440 */
#define STREAM_SHORTS (NWAVE * WAVE_SHORTS) /* 1515520 */

typedef short short8 __attribute__((ext_vector_type(8)));
typedef float floatx16 __attribute__((ext_vector_type(16)));

__device__ __forceinline__ unsigned short f2bf(float f) {
  unsigned int u = __float_as_uint(f);
  u += 0x7FFFu + ((u >> 16) & 1u);
  return (unsigned short)(u >> 16);
}
__device__ __forceinline__ float fsig(float x) {
  return __builtin_amdgcn_rcpf(1.0f + __builtin_amdgcn_exp2f(x * -1.4426950408889634f));
}
__device__ __forceinline__ float ftanh(float x) {
  return 1.0f - 2.0f * __builtin_amdgcn_rcpf(1.0f + __builtin_amdgcn_exp2f(x * 2.8853900817779268f));
}

// Pack all weights (bf16) into the unified per-(wave,group,frag,lane) stream.
// Group gi<32: K-slice gi of h (H=512). frags 0,1 -> W1 (z); frags 2..9 -> W_hh (g,s).
// Group gi>=32: K-slice of the 80-wide ext input. frags 0,1 -> ZERO (zacc padding);
//   frags 2..9 -> W_ih rearranged cols [noise 0..63][gap0][gap1][dp=0][clus][pad..79].
__global__ void prep_pack(const float* __restrict__ Wih, const float* __restrict__ Whh,
                          const float* __restrict__ W1u, unsigned short* __restrict__ us) {
  const int idx = blockIdx.x * blockDim.x + threadIdx.x;
  if (idx >= STREAM_SHORTS / 8) return;
  const int lane = idx & 63;
  const int fragid = idx >> 6;
  const int f = fragid % 10;
  const int gi = (fragid / 10) % NGRP;
  const int w = fragid / (10 * NGRP);
  const int l31 = lane & 31, half = lane >> 5;
  unsigned short v8[8];
  if (gi < 32) {
    const int k0 = gi * 16 + half * 8;
    if (f < 2) {
      const int n = w * 64 + f * 32 + l31;
#pragma unroll
      for (int j = 0; j < 8; ++j) v8[j] = f2bf(W1u[n * Hn + k0 + j]);
    } else {
      const int g = (f - 2) >> 1, s = (f - 2) & 1;
      const int n = g * Hn + w * 64 + s * 32 + l31;
#pragma unroll
      for (int j = 0; j < 8; ++j) v8[j] = f2bf(Whh[n * Hn + k0 + j]);
    }
  } else {
    const int kk = gi - 32;
    const int cb = kk * 16 + half * 8;
    if (f < 2) {
#pragma unroll
      for (int j = 0; j < 8; ++j) v8[j] = 0;
    } else {
      const int g = (f - 2) >> 1, s = (f - 2) & 1;
      const int n = g * Hn + w * 64 + s * 32 + l31;
#pragma unroll
      for (int j = 0; j < 8; ++j) {
        const int c = cb + j;
        float v = 0.0f;
        if (c < 64) v = Wih[n * INn + 3 + c];
        else if (c == 64) v = Wih[n * INn + 0];
        else if (c == 65) v = Wih[n * INn + 1];
        else if (c == 67) v = Wih[n * INn + 67];
        v8[j] = f2bf(v);
      }
    }
  }
  unsigned short* dst = us + (size_t)idx * 8;
#pragma unroll
  for (int j = 0; j < 8; ++j) dst[j] = v8[j];
}

// Persistent recurrent kernel: each block owns 32 batch rows for all 256 steps.
// Weight loop is a 3-buffer rotation (load group g+2 while consuming g) so ~20
// 1KB loads stay in flight per wave; groups 0-1 of the next step are re-issued
// during the epilogue (weights are step-invariant).
__launch_bounds__(NTHREADS, 2)
__global__ void lstm_seq(const float* __restrict__ noise, const float* __restrict__ cluster,
                         const float* __restrict__ gap, const float* __restrict__ Wih,
                         const float* __restrict__ bih, const float* __restrict__ bhh,
                         const float* __restrict__ b1p, const float* __restrict__ W2p,
                         const float* __restrict__ b2p,
                         const unsigned short* __restrict__ us,
                         float* __restrict__ out) {
  __shared__ __align__(16) unsigned short hA[MB * Hn];      // 32 KB, swizzled A-layout
  __shared__ __align__(16) unsigned short extA[MB * 128];   // 8 KB, swizzled
  __shared__ float partial[NWAVE][MB];
  __shared__ float dp_lds[MB];

  const int tid = threadIdx.x;
  const int w = tid >> 6;
  const int lane = tid & 63;
  const int l31 = lane & 31;
  const int half = lane >> 5;
  const int r0 = blockIdx.x * MB;
  const int cb = w * 64;
  const int c0 = cb + l31;
  const int c1 = cb + 32 + l31;

  short8 zero8 = {0, 0, 0, 0, 0, 0, 0, 0};
  for (int i = tid; i < MB * Hn / 8; i += NTHREADS) ((short8*)hA)[i] = zero8;
  for (int i = tid; i < MB * 128 / 8; i += NTHREADS) ((short8*)extA)[i] = zero8;

  float biasv[4][2], wih2[4][2];
#pragma unroll
  for (int g = 0; g < 4; ++g)
#pragma unroll
    for (int s = 0; s < 2; ++s) {
      int n = g * Hn + cb + s * 32 + l31;
      biasv[g][s] = bih[n] + bhh[n];
      wih2[g][s] = Wih[n * INn + 2];
    }
  const float b1v0 = b1p[c0], b1v1 = b1p[c1];
  const float w2v0 = W2p[c0], w2v1 = W2p[c1];
  const float b2v = b2p[0];
  const float clusf = cluster[r0 + (tid & 31)];

  // per-lane base of this wave's weight stream (short8 units)
  const short8* const ws = (const short8*)us + (size_t)w * (NGRP * 10 * 64) + lane;

  // stage extras for t = 0
  {
    const int row = tid >> 4, kq = (tid & 15) << 2;
    const float4 v = *(const float4*)(noise + ((size_t)(r0 + row) * Tn + 0) * NZ + kq);
    ushort4 hb;
    hb.x = f2bf(v.x); hb.y = f2bf(v.y); hb.z = f2bf(v.z); hb.w = f2bf(v.w);
    *(ushort4*)((char*)extA + row * 256 + ((kq << 1) ^ ((row & 15) << 4))) = hb;
    if (tid < MB) {
      const size_t gb = ((size_t)(r0 + tid) * (Tn + 1) + 0) * 2;
      ushort4 hg;
      hg.x = f2bf(gap[gb]); hg.y = f2bf(gap[gb + 1]); hg.z = 0; hg.w = f2bf(clusf);
      *(ushort4*)((char*)extA + tid * 256 + (128 ^ ((tid & 15) << 4))) = hg;
    }
  }

  float c_reg0[16], c_reg1[16];
#pragma unroll
  for (int q = 0; q < 16; ++q) { c_reg0[q] = 0.f; c_reg1[q] = 0.f; }

  __syncthreads();

  // 3 register group-buffers (static names only — no runtime indexing)
  short8 bA[10], bB[10], bC[10];

  auto ldgrp = [&](int g, short8(&b)[10]) {
    const short8* p = ws + g * (10 * 64);
#pragma unroll
    for (int f = 0; f < 10; ++f) b[f] = p[f * 64];
  };

  // prologue prefetch for t = 0
  ldgrp(0, bA);
  ldgrp(1, bB);

  for (int t = 0; t <= Tn; ++t) {
    floatx16 zacc[2];
    floatx16 acc[4][2];
#pragma unroll
    for (int s = 0; s < 2; ++s)
#pragma unroll
      for (int q = 0; q < 16; ++q) zacc[s][q] = 0.f;
#pragma unroll
    for (int g = 0; g < 4; ++g)
#pragma unroll
      for (int s = 0; s < 2; ++s)
#pragma unroll
        for (int q = 0; q < 16; ++q) acc[g][s][q] = 0.f;

    // branchless A-fragment fetch + 10 MFMAs for group g
    auto consume = [&](int g, const short8(&b)[10]) {
      const int isH = (g < 32) ? 1 : 0;
      const int gg = isH ? g : (g - 32);
      const int k0 = (gg << 4) + (half << 3);
      const int rsh = isH ? 10 : 8;
      const int msk = isH ? l31 : (l31 & 15);
      const char* base = isH ? (const char*)hA : (const char*)extA;
      const short8 a = *(const short8*)(base + (l31 << rsh) + ((k0 << 1) ^ (msk << 4)));
      zacc[0] = __builtin_amdgcn_mfma_f32_32x32x16_bf16(a, b[0], zacc[0], 0, 0, 0);
      zacc[1] = __builtin_amdgcn_mfma_f32_32x32x16_bf16(a, b[1], zacc[1], 0, 0, 0);
#pragma unroll
      for (int g2 = 0; g2 < 4; ++g2)
#pragma unroll
        for (int s = 0; s < 2; ++s)
          acc[g2][s] = __builtin_amdgcn_mfma_f32_32x32x16_bf16(a, b[2 + g2 * 2 + s], acc[g2][s], 0, 0, 0);
    };

    // main 3-buffer rotation: ii = 0..10 covers groups 0..32
    for (int ii = 0; ii < 11; ++ii) {
      const int g0 = 3 * ii;
      ldgrp(g0 + 2, bC); consume(g0, bA);
      ldgrp(g0 + 3, bA); consume(g0 + 1, bB);
      ldgrp(g0 + 4, bB); consume(g0 + 2, bC);
    }
    // tail: groups 33..36
    ldgrp(35, bC); consume(33, bA);
    ldgrp(36, bA); consume(34, bB);
    consume(35, bC);
    consume(36, bA);
    // cross-step prefetch: weights are identical every step; these land
    // under the epilogue barriers instead of cold-starting the next step.
    ldgrp(0, bA);
    ldgrp(1, bB);

    // z finish + dp partials
    {
      float part[16];
#pragma unroll
      for (int q = 0; q < 16; ++q) {
        const float z0 = ftanh(zacc[0][q] + b1v0);
        const float z1 = ftanh(zacc[1][q] + b1v1);
        part[q] = z0 * w2v0 + z1 * w2v1;
      }
#pragma unroll
      for (int m = 1; m <= 16; m <<= 1)
#pragma unroll
        for (int q = 0; q < 16; ++q) part[q] += __shfl_xor(part[q], m, 64);
      if (l31 == 0) {
#pragma unroll
        for (int q = 0; q < 16; ++q)
          partial[w][(q & 3) + ((q >> 2) << 3) + (half << 2)] = part[q];
      }
    }

    __syncthreads();  // B1: partial complete; all reads of hA/extA complete

    if (tid < MB) {
      float ssum = b2v;
#pragma unroll
      for (int ww = 0; ww < NWAVE; ++ww) ssum += partial[ww][tid];
      const float dpv = DPRv * ftanh(ssum);
      dp_lds[tid] = dpv;
      const size_t gb = ((size_t)(r0 + tid) * (Tn + 1) + t) * 2;
      const float g0 = gap[gb], g1 = gap[gb + 1];
      float* op = out + ((size_t)(r0 + tid) * (Tn + 1) + t) * 3;
      op[0] = g0; op[1] = g1; op[2] = dpv;
    }
    if (t < Tn - 1) {
      const int row = tid >> 4, kq = (tid & 15) << 2;
      const float4 v = *(const float4*)(noise + ((size_t)(r0 + row) * Tn + (t + 1)) * NZ + kq);
      ushort4 hb;
      hb.x = f2bf(v.x); hb.y = f2bf(v.y); hb.z = f2bf(v.z); hb.w = f2bf(v.w);
      *(ushort4*)((char*)extA + row * 256 + ((kq << 1) ^ ((row & 15) << 4))) = hb;
      if (tid < MB) {
        const size_t gb = ((size_t)(r0 + tid) * (Tn + 1) + (t + 1)) * 2;
        ushort4 hg;
        hg.x = f2bf(gap[gb]); hg.y = f2bf(gap[gb + 1]); hg.z = 0; hg.w = f2bf(clusf);
        *(ushort4*)((char*)extA + tid * 256 + (128 ^ ((tid & 15) << 4))) = hg;
      }
    }
    __syncthreads();  // B2: dp_lds visible; hA safe to overwrite

    if (t < Tn) {
      float dpv[16];
#pragma unroll
      for (int q = 0; q < 16; ++q)
        dpv[q] = dp_lds[(q & 3) + ((q >> 2) << 3) + (half << 2)];
#pragma unroll
      for (int s = 0; s < 2; ++s) {
        const int colb = (cb + s * 32 + l31) << 1;
#pragma unroll
        for (int q = 0; q < 16; ++q) {
          const float gi = acc[0][s][q] + biasv[0][s] + dpv[q] * wih2[0][s];
          const float gf = acc[1][s][q] + biasv[1][s] + dpv[q] * wih2[1][s];
          const float gg = acc[2][s][q] + biasv[2][s] + dpv[q] * wih2[2][s];
          const float go = acc[3][s][q] + biasv[3][s] + dpv[q] * wih2[3][s];
          float cv = (s == 0) ? c_reg0[q] : c_reg1[q];
          cv = fsig(gf) * cv + fsig(gi) * ftanh(gg);
          const float hv = fsig(go) * ftanh(cv);
          if (s == 0) c_reg0[q] = cv; else c_reg1[q] = cv;
          const int r = (q & 3) + ((q >> 2) << 3) + (half << 2);
          *(unsigned short*)((char*)hA + (r << 10) + (colb ^ (r << 4))) = f2bf(hv);
        }
      }
    }
    __syncthreads();  // B3: hA ready for next step
  }
}

extern "C" void kernel_launch(void* const* d_in, const int* in_sizes, int n_in,
                              void* d_out, int out_size, void* d_ws, size_t ws_size,
                              hipStream_t stream) {
  const float* noise   = (const float*)d_in[0];
  const float* cluster = (const float*)d_in[1];
  const float* gap     = (const float*)d_in[2];
  const float* Wih     = (const float*)d_in[3];
  const float* Whh     = (const float*)d_in[4];
  const float* bih     = (const float*)d_in[5];
  const float* bhh     = (const float*)d_in[6];
  const float* W1      = (const float*)d_in[7];
  const float* b1      = (const float*)d_in[8];
  const float* W2      = (const float*)d_in[9];
  const float* b2      = (const float*)d_in[10];

  unsigned short* us = (unsigned short*)d_ws;  // 1,515,520 shorts = 3.03 MB

  prep_pack<<<(STREAM_SHORTS / 8 + 255) / 256, 256, 0, stream>>>(Wih, Whh, W1, us);
  lstm_seq<<<NBLK, NTHREADS, 0, stream>>>(noise, cluster, gap, Wih, bih, bhh, b1, W2, b2,
                                          us, (float*)d_out);
}

// Round 8
// 14938.725 us; speedup vs baseline: 3.6163x; 3.6163x over previous
//
#include <hip/hip_runtime.h>

#define Bn 4096
#define Tn 256
#define NZ 64
#define Hn 512
#define INn 68
#define DPRv 24.0f
#define MB 32
#define NWAVE 8
#define NTHREADS 512
#define NBLK 128

// unified per-wave weight stream: 37 groups (32 h + 5 ext) x 10 frags x 64 lanes x 8 shorts
// consumed as 74 half-groups of 5 frags.
#define NGRP 37
#define NHALF (NGRP * 2) /* 74 */
#define GRP_SHORTS (10 * 64 * 8)            /* 5120 */
#define WAVE_SHORTS (NGRP * GRP_SHORTS)     /* 189440 */
#define STREAM_SHORTS (NWAVE * WAVE_SHORTS) /* 1515520 */

typedef short short8 __attribute__((ext_vector_type(8)));
typedef float floatx16 __attribute__((ext_vector_type(16)));
typedef float f4v __attribute__((ext_vector_type(4)));

__device__ __forceinline__ unsigned short f2bf(float f) {
  unsigned int u = __float_as_uint(f);
  u += 0x7FFFu + ((u >> 16) & 1u);
  return (unsigned short)(u >> 16);
}
__device__ __forceinline__ float fsig(float x) {
  return __builtin_amdgcn_rcpf(1.0f + __builtin_amdgcn_exp2f(x * -1.4426950408889634f));
}
__device__ __forceinline__ float ftanh(float x) {
  return 1.0f - 2.0f * __builtin_amdgcn_rcpf(1.0f + __builtin_amdgcn_exp2f(x * 2.8853900817779268f));
}

// Pack all weights (bf16) into the unified per-(wave,group,frag,lane) stream.
// Group gi<32: K-slice gi of h (H=512). frags 0,1 -> W1 (z); frags 2..9 -> W_hh (g,s).
// Group gi>=32: K-slice of the 80-wide ext input. frags 0,1 -> ZERO (zacc padding);
//   frags 2..9 -> W_ih rearranged cols [noise 0..63][gap0][gap1][dp=0][clus][pad..79].
__global__ void prep_pack(const float* __restrict__ Wih, const float* __restrict__ Whh,
                          const float* __restrict__ W1u, unsigned short* __restrict__ us) {
  const int idx = blockIdx.x * blockDim.x + threadIdx.x;
  if (idx >= STREAM_SHORTS / 8) return;
  const int lane = idx & 63;
  const int fragid = idx >> 6;
  const int f = fragid % 10;
  const int gi = (fragid / 10) % NGRP;
  const int w = fragid / (10 * NGRP);
  const int l31 = lane & 31, half = lane >> 5;
  unsigned short v8[8];
  if (gi < 32) {
    const int k0 = gi * 16 + half * 8;
    if (f < 2) {
      const int n = w * 64 + f * 32 + l31;
#pragma unroll
      for (int j = 0; j < 8; ++j) v8[j] = f2bf(W1u[n * Hn + k0 + j]);
    } else {
      const int g = (f - 2) >> 1, s = (f - 2) & 1;
      const int n = g * Hn + w * 64 + s * 32 + l31;
#pragma unroll
      for (int j = 0; j < 8; ++j) v8[j] = f2bf(Whh[n * Hn + k0 + j]);
    }
  } else {
    const int kk = gi - 32;
    const int cb = kk * 16 + half * 8;
    if (f < 2) {
#pragma unroll
      for (int j = 0; j < 8; ++j) v8[j] = 0;
    } else {
      const int g = (f - 2) >> 1, s = (f - 2) & 1;
      const int n = g * Hn + w * 64 + s * 32 + l31;
#pragma unroll
      for (int j = 0; j < 8; ++j) {
        const int c = cb + j;
        float v = 0.0f;
        if (c < 64) v = Wih[n * INn + 3 + c];
        else if (c == 64) v = Wih[n * INn + 0];
        else if (c == 65) v = Wih[n * INn + 1];
        else if (c == 67) v = Wih[n * INn + 67];
        v8[j] = f2bf(v);
      }
    }
  }
  unsigned short* dst = us + (size_t)idx * 8;
#pragma unroll
  for (int j = 0; j < 8; ++j) dst[j] = v8[j];
}

// Persistent recurrent kernel: each block owns 32 batch rows for all 256 steps.
// Weight stream consumed as 74 half-groups of 5 fragments with a 4-buffer
// rotation (same 80 buffer-VGPRs as the passing R5 kernel, but ~2.5 half-groups
// in flight instead of 1). noise/gap/out use non-temporal accesses so the 3MB
// weight stream stays L2-resident across steps.
__launch_bounds__(NTHREADS, 2)
__global__ void lstm_seq(const float* __restrict__ noise, const float* __restrict__ cluster,
                         const float* __restrict__ gap, const float* __restrict__ Wih,
                         const float* __restrict__ bih, const float* __restrict__ bhh,
                         const float* __restrict__ b1p, const float* __restrict__ W2p,
                         const float* __restrict__ b2p,
                         const unsigned short* __restrict__ us,
                         float* __restrict__ out) {
  __shared__ __align__(16) unsigned short hA[MB * Hn];      // 32 KB, swizzled A-layout
  __shared__ __align__(16) unsigned short extA[MB * 128];   // 8 KB, swizzled
  __shared__ float partial[NWAVE][MB];
  __shared__ float dp_lds[MB];

  const int tid = threadIdx.x;
  const int w = tid >> 6;
  const int lane = tid & 63;
  const int l31 = lane & 31;
  const int half = lane >> 5;
  const int r0 = blockIdx.x * MB;
  const int cb = w * 64;
  const int c0 = cb + l31;
  const int c1 = cb + 32 + l31;

  short8 zero8 = {0, 0, 0, 0, 0, 0, 0, 0};
  for (int i = tid; i < MB * Hn / 8; i += NTHREADS) ((short8*)hA)[i] = zero8;
  for (int i = tid; i < MB * 128 / 8; i += NTHREADS) ((short8*)extA)[i] = zero8;

  float biasv[4][2], wih2[4][2];
#pragma unroll
  for (int g = 0; g < 4; ++g)
#pragma unroll
    for (int s = 0; s < 2; ++s) {
      int n = g * Hn + cb + s * 32 + l31;
      biasv[g][s] = bih[n] + bhh[n];
      wih2[g][s] = Wih[n * INn + 2];
    }
  const float b1v0 = b1p[c0], b1v1 = b1p[c1];
  const float w2v0 = W2p[c0], w2v1 = W2p[c1];
  const float b2v = b2p[0];
  const float clusf = cluster[r0 + (tid & 31)];

  // per-lane base of this wave's weight stream (short8 units)
  const short8* const ws = (const short8*)us + (size_t)w * (NGRP * 10 * 64) + lane;

  // stage extras for t = 0
  {
    const int row = tid >> 4, kq = (tid & 15) << 2;
    const f4v v = __builtin_nontemporal_load(
        (const f4v*)(noise + ((size_t)(r0 + row) * Tn + 0) * NZ + kq));
    ushort4 hb;
    hb.x = f2bf(v.x); hb.y = f2bf(v.y); hb.z = f2bf(v.z); hb.w = f2bf(v.w);
    *(ushort4*)((char*)extA + row * 256 + ((kq << 1) ^ ((row & 15) << 4))) = hb;
    if (tid < MB) {
      const size_t gb = ((size_t)(r0 + tid) * (Tn + 1) + 0) * 2;
      ushort4 hg;
      hg.x = f2bf(gap[gb]); hg.y = f2bf(gap[gb + 1]); hg.z = 0; hg.w = f2bf(clusf);
      *(ushort4*)((char*)extA + tid * 256 + (128 ^ ((tid & 15) << 4))) = hg;
    }
  }

  float c_reg0[16], c_reg1[16];
#pragma unroll
  for (int q = 0; q < 16; ++q) { c_reg0[q] = 0.f; c_reg1[q] = 0.f; }

  __syncthreads();

  // 4 register half-group buffers (static names only — no runtime indexing)
  short8 bA[5], bB[5], bC[5], bD[5];

  auto ldh = [&](int g2, short8(&b)[5]) {
    const short8* p = ws + g2 * (5 * 64);
#pragma unroll
    for (int f = 0; f < 5; ++f) b[f] = p[f * 64];
  };

  // prologue prefetch for t = 0
  ldh(0, bA);
  ldh(1, bB);
  ldh(2, bC);

  for (int t = 0; t <= Tn; ++t) {
    floatx16 zacc[2];
    floatx16 acc[4][2];
#pragma unroll
    for (int s = 0; s < 2; ++s)
#pragma unroll
      for (int q = 0; q < 16; ++q) zacc[s][q] = 0.f;
#pragma unroll
    for (int g = 0; g < 4; ++g)
#pragma unroll
      for (int s = 0; s < 2; ++s)
#pragma unroll
        for (int q = 0; q < 16; ++q) acc[g][s][q] = 0.f;

    // branchless A-fragment fetch for group g (= g2>>1)
    auto afrag = [&](int g2) -> short8 {
      const int g = g2 >> 1;
      const int isH = (g < 32) ? 1 : 0;
      const int gg = isH ? g : (g - 32);
      const int k0 = (gg << 4) + (half << 3);
      const int rsh = isH ? 10 : 8;
      const int msk = isH ? l31 : (l31 & 15);
      const char* base = isH ? (const char*)hA : (const char*)extA;
      return *(const short8*)(base + (l31 << rsh) + ((k0 << 1) ^ (msk << 4)));
    };
    // even half: frags 0..4 = [z0, z1, g0s0, g0s1, g1s0]
    auto cons0 = [&](int g2, const short8(&b)[5]) {
      const short8 a = afrag(g2);
      zacc[0]   = __builtin_amdgcn_mfma_f32_32x32x16_bf16(a, b[0], zacc[0], 0, 0, 0);
      zacc[1]   = __builtin_amdgcn_mfma_f32_32x32x16_bf16(a, b[1], zacc[1], 0, 0, 0);
      acc[0][0] = __builtin_amdgcn_mfma_f32_32x32x16_bf16(a, b[2], acc[0][0], 0, 0, 0);
      acc[0][1] = __builtin_amdgcn_mfma_f32_32x32x16_bf16(a, b[3], acc[0][1], 0, 0, 0);
      acc[1][0] = __builtin_amdgcn_mfma_f32_32x32x16_bf16(a, b[4], acc[1][0], 0, 0, 0);
    };
    // odd half: frags 5..9 = [g1s1, g2s0, g2s1, g3s0, g3s1]
    auto cons1 = [&](int g2, const short8(&b)[5]) {
      const short8 a = afrag(g2);
      acc[1][1] = __builtin_amdgcn_mfma_f32_32x32x16_bf16(a, b[0], acc[1][1], 0, 0, 0);
      acc[2][0] = __builtin_amdgcn_mfma_f32_32x32x16_bf16(a, b[1], acc[2][0], 0, 0, 0);
      acc[2][1] = __builtin_amdgcn_mfma_f32_32x32x16_bf16(a, b[2], acc[2][1], 0, 0, 0);
      acc[3][0] = __builtin_amdgcn_mfma_f32_32x32x16_bf16(a, b[3], acc[3][0], 0, 0, 0);
      acc[3][1] = __builtin_amdgcn_mfma_f32_32x32x16_bf16(a, b[4], acc[3][1], 0, 0, 0);
    };

    // 4-buffer rotation: 17 iters cover halves 0..67 (loads reach 70)
    for (int ii = 0; ii < 17; ++ii) {
      const int g0 = 4 * ii;
      ldh(g0 + 3, bD); cons0(g0, bA);
      ldh(g0 + 4, bA); cons1(g0 + 1, bB);
      ldh(g0 + 5, bB); cons0(g0 + 2, bC);
      ldh(g0 + 6, bC); cons1(g0 + 3, bD);
    }
    // tail: halves 68..73
    ldh(71, bD); cons0(68, bA);
    ldh(72, bA); cons1(69, bB);
    ldh(73, bB); cons0(70, bC);
    cons1(71, bD);
    cons0(72, bA);
    cons1(73, bB);
    // cross-step prefetch (weights are step-invariant): lands under epilogue
    ldh(0, bA);
    ldh(1, bB);
    ldh(2, bC);

    // z finish + dp partials
    {
      float part[16];
#pragma unroll
      for (int q = 0; q < 16; ++q) {
        const float z0 = ftanh(zacc[0][q] + b1v0);
        const float z1 = ftanh(zacc[1][q] + b1v1);
        part[q] = z0 * w2v0 + z1 * w2v1;
      }
#pragma unroll
      for (int m = 1; m <= 16; m <<= 1)
#pragma unroll
        for (int q = 0; q < 16; ++q) part[q] += __shfl_xor(part[q], m, 64);
      if (l31 == 0) {
#pragma unroll
        for (int q = 0; q < 16; ++q)
          partial[w][(q & 3) + ((q >> 2) << 3) + (half << 2)] = part[q];
      }
    }

    __syncthreads();  // B1: partial complete; all reads of hA/extA complete

    if (tid < MB) {
      float ssum = b2v;
#pragma unroll
      for (int ww = 0; ww < NWAVE; ++ww) ssum += partial[ww][tid];
      const float dpv = DPRv * ftanh(ssum);
      dp_lds[tid] = dpv;
      const size_t gb = ((size_t)(r0 + tid) * (Tn + 1) + t) * 2;
      const float g0 = __builtin_nontemporal_load(gap + gb);
      const float g1 = __builtin_nontemporal_load(gap + gb + 1);
      float* op = out + ((size_t)(r0 + tid) * (Tn + 1) + t) * 3;
      __builtin_nontemporal_store(g0, op);
      __builtin_nontemporal_store(g1, op + 1);
      __builtin_nontemporal_store(dpv, op + 2);
    }
    if (t < Tn - 1) {
      const int row = tid >> 4, kq = (tid & 15) << 2;
      const f4v v = __builtin_nontemporal_load(
          (const f4v*)(noise + ((size_t)(r0 + row) * Tn + (t + 1)) * NZ + kq));
      ushort4 hb;
      hb.x = f2bf(v.x); hb.y = f2bf(v.y); hb.z = f2bf(v.z); hb.w = f2bf(v.w);
      *(ushort4*)((char*)extA + row * 256 + ((kq << 1) ^ ((row & 15) << 4))) = hb;
      if (tid < MB) {
        const size_t gb = ((size_t)(r0 + tid) * (Tn + 1) + (t + 1)) * 2;
        const float g0 = __builtin_nontemporal_load(gap + gb);
        const float g1 = __builtin_nontemporal_load(gap + gb + 1);
        ushort4 hg;
        hg.x = f2bf(g0); hg.y = f2bf(g1); hg.z = 0; hg.w = f2bf(clusf);
        *(ushort4*)((char*)extA + tid * 256 + (128 ^ ((tid & 15) << 4))) = hg;
      }
    }
    __syncthreads();  // B2: dp_lds visible; hA safe to overwrite

    if (t < Tn) {
      float dpv[16];
#pragma unroll
      for (int q = 0; q < 16; ++q)
        dpv[q] = dp_lds[(q & 3) + ((q >> 2) << 3) + (half << 2)];
#pragma unroll
      for (int s = 0; s < 2; ++s) {
        const int colb = (cb + s * 32 + l31) << 1;
#pragma unroll
        for (int q = 0; q < 16; ++q) {
          const float gi = acc[0][s][q] + biasv[0][s] + dpv[q] * wih2[0][s];
          const float gf = acc[1][s][q] + biasv[1][s] + dpv[q] * wih2[1][s];
          const float gg = acc[2][s][q] + biasv[2][s] + dpv[q] * wih2[2][s];
          const float go = acc[3][s][q] + biasv[3][s] + dpv[q] * wih2[3][s];
          float cv = (s == 0) ? c_reg0[q] : c_reg1[q];
          cv = fsig(gf) * cv + fsig(gi) * ftanh(gg);
          const float hv = fsig(go) * ftanh(cv);
          if (s == 0) c_reg0[q] = cv; else c_reg1[q] = cv;
          const int r = (q & 3) + ((q >> 2) << 3) + (half << 2);
          *(unsigned short*)((char*)hA + (r << 10) + (colb ^ (r << 4))) = f2bf(hv);
        }
      }
    }
    __syncthreads();  // B3: hA ready for next step
  }
}

extern "C" void kernel_launch(void* const* d_in, const int* in_sizes, int n_in,
                              void* d_out, int out_size, void* d_ws, size_t ws_size,
                              hipStream_t stream) {
  const float* noise   = (const float*)d_in[0];
  const float* cluster = (const float*)d_in[1];
  const float* gap     = (const float*)d_in[2];
  const float* Wih     = (const float*)d_in[3];
  const float* Whh     = (const float*)d_in[4];
  const float* bih     = (const float*)d_in[5];
  const float* bhh     = (const float*)d_in[6];
  const float* W1      = (const float*)d_in[7];
  const float* b1      = (const float*)d_in[8];
  const float* W2      = (const float*)d_in[9];
  const float* b2      = (const float*)d_in[10];

  unsigned short* us = (unsigned short*)d_ws;  // 1,515,520 shorts = 3.03 MB

  prep_pack<<<(STREAM_SHORTS / 8 + 255) / 256, 256, 0, stream>>>(Wih, Whh, W1, us);
  lstm_seq<<<NBLK, NTHREADS, 0, stream>>>(noise, cluster, gap, Wih, bih, bhh, b1, W2, b2,
                                          us, (float*)d_out);
}

// Round 9
// 11654.630 us; speedup vs baseline: 4.6353x; 1.2818x over previous
//
#include <hip/hip_runtime.h>

#define Bn 4096
#define Tn 256
#define NZ 64
#define Hn 512
#define INn 68
#define DPRv 24.0f
#define MB 32
#define NWAVE 8
#define NTHREADS 512
#define NBLK 128

// unified per-wave weight stream: 37 groups (32 h + 5 ext) x 10 frags x 64 lanes x 8 shorts
#define NGRP 37
#define GRP_SHORTS (10 * 64 * 8)            /* 5120 */
#define WAVE_SHORTS (NGRP * GRP_SHORTS)     /* 189440 */
#define STREAM_SHORTS (NWAVE * WAVE_SHORTS) /* 1515520 */

typedef short short8 __attribute__((ext_vector_type(8)));
typedef float floatx16 __attribute__((ext_vector_type(16)));

__device__ __forceinline__ unsigned short f2bf(float f) {
  unsigned int u = __float_as_uint(f);
  u += 0x7FFFu + ((u >> 16) & 1u);
  return (unsigned short)(u >> 16);
}
__device__ __forceinline__ float fsig(float x) {
  return __builtin_amdgcn_rcpf(1.0f + __builtin_amdgcn_exp2f(x * -1.4426950408889634f));
}
__device__ __forceinline__ float ftanh(float x) {
  return 1.0f - 2.0f * __builtin_amdgcn_rcpf(1.0f + __builtin_amdgcn_exp2f(x * 2.8853900817779268f));
}

// Pack all weights (bf16) into the unified per-(wave,group,frag,lane) stream.
// Group gi<32: K-slice gi of h (H=512). frags 0,1 -> W1 (z); frags 2..9 -> W_hh (g,s).
// Group gi>=32: K-slice of the 80-wide ext input. frags 0,1 -> ZERO (zacc padding);
//   frags 2..9 -> W_ih rearranged cols [noise 0..63][gap0][gap1][dp=0][clus][pad..79].
__global__ void prep_pack(const float* __restrict__ Wih, const float* __restrict__ Whh,
                          const float* __restrict__ W1u, unsigned short* __restrict__ us) {
  const int idx = blockIdx.x * blockDim.x + threadIdx.x;
  if (idx >= STREAM_SHORTS / 8) return;
  const int lane = idx & 63;
  const int fragid = idx >> 6;
  const int f = fragid % 10;
  const int gi = (fragid / 10) % NGRP;
  const int w = fragid / (10 * NGRP);
  const int l31 = lane & 31, half = lane >> 5;
  unsigned short v8[8];
  if (gi < 32) {
    const int k0 = gi * 16 + half * 8;
    if (f < 2) {
      const int n = w * 64 + f * 32 + l31;
#pragma unroll
      for (int j = 0; j < 8; ++j) v8[j] = f2bf(W1u[n * Hn + k0 + j]);
    } else {
      const int g = (f - 2) >> 1, s = (f - 2) & 1;
      const int n = g * Hn + w * 64 + s * 32 + l31;
#pragma unroll
      for (int j = 0; j < 8; ++j) v8[j] = f2bf(Whh[n * Hn + k0 + j]);
    }
  } else {
    const int kk = gi - 32;
    const int cb = kk * 16 + half * 8;
    if (f < 2) {
#pragma unroll
      for (int j = 0; j < 8; ++j) v8[j] = 0;
    } else {
      const int g = (f - 2) >> 1, s = (f - 2) & 1;
      const int n = g * Hn + w * 64 + s * 32 + l31;
#pragma unroll
      for (int j = 0; j < 8; ++j) {
        const int c = cb + j;
        float v = 0.0f;
        if (c < 64) v = Wih[n * INn + 3 + c];
        else if (c == 64) v = Wih[n * INn + 0];
        else if (c == 65) v = Wih[n * INn + 1];
        else if (c == 67) v = Wih[n * INn + 67];
        v8[j] = f2bf(v);
      }
    }
  }
  unsigned short* dst = us + (size_t)idx * 8;
#pragma unroll
  for (int j = 0; j < 8; ++j) dst[j] = v8[j];
}

// Persistent recurrent kernel: each block owns 32 batch rows for all 256 steps.
// Weight loop is the proven R5 2-buffer rotation, PLUS a per-block phase
// rotation of the (commutative) group sweep: the 16 blocks of an XCD start
// at staggered offsets in the 3MB weight stream, so the stream has no single
// LRU sweep front and stays L2-resident across steps.
__launch_bounds__(NTHREADS, 2)
__global__ void lstm_seq(const float* __restrict__ noise, const float* __restrict__ cluster,
                         const float* __restrict__ gap, const float* __restrict__ Wih,
                         const float* __restrict__ bih, const float* __restrict__ bhh,
                         const float* __restrict__ b1p, const float* __restrict__ W2p,
                         const float* __restrict__ b2p,
                         const unsigned short* __restrict__ us,
                         float* __restrict__ out) {
  __shared__ __align__(16) unsigned short hA[MB * Hn];      // 32 KB, swizzled A-layout
  __shared__ __align__(16) unsigned short extA[MB * 128];   // 8 KB, swizzled
  __shared__ float partial[NWAVE][MB];
  __shared__ float dp_lds[MB];

  const int tid = threadIdx.x;
  const int w = tid >> 6;
  const int lane = tid & 63;
  const int l31 = lane & 31;
  const int half = lane >> 5;
  const int r0 = blockIdx.x * MB;
  const int cb = w * 64;
  const int c0 = cb + l31;
  const int c1 = cb + 32 + l31;

  // phase rotation: blocks on the same XCD (bid%8 fixed) get staggered starts
  const int koff = (((blockIdx.x >> 3) & 15) * NGRP) >> 4;  // 0..34, even spread

  short8 zero8 = {0, 0, 0, 0, 0, 0, 0, 0};
  for (int i = tid; i < MB * Hn / 8; i += NTHREADS) ((short8*)hA)[i] = zero8;
  for (int i = tid; i < MB * 128 / 8; i += NTHREADS) ((short8*)extA)[i] = zero8;

  float biasv[4][2], wih2[4][2];
#pragma unroll
  for (int g = 0; g < 4; ++g)
#pragma unroll
    for (int s = 0; s < 2; ++s) {
      int n = g * Hn + cb + s * 32 + l31;
      biasv[g][s] = bih[n] + bhh[n];
      wih2[g][s] = Wih[n * INn + 2];
    }
  const float b1v0 = b1p[c0], b1v1 = b1p[c1];
  const float w2v0 = W2p[c0], w2v1 = W2p[c1];
  const float b2v = b2p[0];
  const float clusf = cluster[r0 + (tid & 31)];

  // per-lane base of this wave's weight stream (short8 units)
  const short8* const ws = (const short8*)us + (size_t)w * (NGRP * 10 * 64) + lane;

  // stage extras for t = 0
  {
    const int row = tid >> 4, kq = (tid & 15) << 2;
    const float4 v = *(const float4*)(noise + ((size_t)(r0 + row) * Tn + 0) * NZ + kq);
    ushort4 hb;
    hb.x = f2bf(v.x); hb.y = f2bf(v.y); hb.z = f2bf(v.z); hb.w = f2bf(v.w);
    *(ushort4*)((char*)extA + row * 256 + ((kq << 1) ^ ((row & 15) << 4))) = hb;
    if (tid < MB) {
      const size_t gb = ((size_t)(r0 + tid) * (Tn + 1) + 0) * 2;
      ushort4 hg;
      hg.x = f2bf(gap[gb]); hg.y = f2bf(gap[gb + 1]); hg.z = 0; hg.w = f2bf(clusf);
      *(ushort4*)((char*)extA + tid * 256 + (128 ^ ((tid & 15) << 4))) = hg;
    }
  }

  float c_reg0[16], c_reg1[16];
#pragma unroll
  for (int q = 0; q < 16; ++q) { c_reg0[q] = 0.f; c_reg1[q] = 0.f; }

  __syncthreads();

  for (int t = 0; t <= Tn; ++t) {
    floatx16 zacc[2];
    floatx16 acc[4][2];
#pragma unroll
    for (int s = 0; s < 2; ++s)
#pragma unroll
      for (int q = 0; q < 16; ++q) zacc[s][q] = 0.f;
#pragma unroll
    for (int g = 0; g < 4; ++g)
#pragma unroll
      for (int s = 0; s < 2; ++s)
#pragma unroll
        for (int q = 0; q < 16; ++q) acc[g][s][q] = 0.f;

    // rotated group index (wave-uniform; single conditional subtract)
    auto wgrp = [&](int g) -> int {
      int x = g + koff;
      return (x >= NGRP) ? (x - NGRP) : x;
    };
    // load all 10 fragments of rotated group g into registers
    auto ldgrp = [&](int g, short8(&b)[10]) {
      const short8* p = ws + wgrp(g) * (10 * 64);
#pragma unroll
      for (int f = 0; f < 10; ++f) b[f] = p[f * 64];
    };
    // branchless A-fragment fetch + 10 MFMAs for rotated group g
    auto consume = [&](int g, const short8(&b)[10]) {
      const int gw = wgrp(g);
      const int isH = (gw < 32) ? 1 : 0;
      const int gg = isH ? gw : (gw - 32);
      const int k0 = (gg << 4) + (half << 3);
      const int rsh = isH ? 10 : 8;
      const int msk = isH ? l31 : (l31 & 15);
      const char* base = isH ? (const char*)hA : (const char*)extA;
      const short8 a = *(const short8*)(base + (l31 << rsh) + ((k0 << 1) ^ (msk << 4)));
      zacc[0] = __builtin_amdgcn_mfma_f32_32x32x16_bf16(a, b[0], zacc[0], 0, 0, 0);
      zacc[1] = __builtin_amdgcn_mfma_f32_32x32x16_bf16(a, b[1], zacc[1], 0, 0, 0);
#pragma unroll
      for (int g2 = 0; g2 < 4; ++g2)
#pragma unroll
        for (int s = 0; s < 2; ++s)
          acc[g2][s] = __builtin_amdgcn_mfma_f32_32x32x16_bf16(a, b[2 + g2 * 2 + s], acc[g2][s], 0, 0, 0);
    };

    short8 bufA[10], bufB[10];
    ldgrp(0, bufA);
    for (int ii = 0; ii < 18; ++ii) {
      const int g0 = 2 * ii;
      ldgrp(g0 + 1, bufB);
      consume(g0, bufA);
      ldgrp(g0 + 2, bufA);   // g0+2 <= 36 always (ii<=17)
      consume(g0 + 1, bufB);
    }
    consume(36, bufA);

    // z finish + dp partials
    {
      float part[16];
#pragma unroll
      for (int q = 0; q < 16; ++q) {
        const float z0 = ftanh(zacc[0][q] + b1v0);
        const float z1 = ftanh(zacc[1][q] + b1v1);
        part[q] = z0 * w2v0 + z1 * w2v1;
      }
#pragma unroll
      for (int m = 1; m <= 16; m <<= 1)
#pragma unroll
        for (int q = 0; q < 16; ++q) part[q] += __shfl_xor(part[q], m, 64);
      if (l31 == 0) {
#pragma unroll
        for (int q = 0; q < 16; ++q)
          partial[w][(q & 3) + ((q >> 2) << 3) + (half << 2)] = part[q];
      }
    }

    __syncthreads();  // B1: partial complete; all reads of hA/extA complete

    if (tid < MB) {
      float ssum = b2v;
#pragma unroll
      for (int ww = 0; ww < NWAVE; ++ww) ssum += partial[ww][tid];
      const float dpv = DPRv * ftanh(ssum);
      dp_lds[tid] = dpv;
      const size_t gb = ((size_t)(r0 + tid) * (Tn + 1) + t) * 2;
      const float g0 = gap[gb], g1 = gap[gb + 1];
      float* op = out + ((size_t)(r0 + tid) * (Tn + 1) + t) * 3;
      op[0] = g0; op[1] = g1; op[2] = dpv;
    }
    if (t < Tn - 1) {
      const int row = tid >> 4, kq = (tid & 15) << 2;
      const float4 v = *(const float4*)(noise + ((size_t)(r0 + row) * Tn + (t + 1)) * NZ + kq);
      ushort4 hb;
      hb.x = f2bf(v.x); hb.y = f2bf(v.y); hb.z = f2bf(v.z); hb.w = f2bf(v.w);
      *(ushort4*)((char*)extA + row * 256 + ((kq << 1) ^ ((row & 15) << 4))) = hb;
      if (tid < MB) {
        const size_t gb = ((size_t)(r0 + tid) * (Tn + 1) + (t + 1)) * 2;
        ushort4 hg;
        hg.x = f2bf(gap[gb]); hg.y = f2bf(gap[gb + 1]); hg.z = 0; hg.w = f2bf(clusf);
        *(ushort4*)((char*)extA + tid * 256 + (128 ^ ((tid & 15) << 4))) = hg;
      }
    }
    __syncthreads();  // B2: dp_lds visible; hA safe to overwrite

    if (t < Tn) {
      float dpv[16];
#pragma unroll
      for (int q = 0; q < 16; ++q)
        dpv[q] = dp_lds[(q & 3) + ((q >> 2) << 3) + (half << 2)];
#pragma unroll
      for (int s = 0; s < 2; ++s) {
        const int colb = (cb + s * 32 + l31) << 1;
#pragma unroll
        for (int q = 0; q < 16; ++q) {
          const float gi = acc[0][s][q] + biasv[0][s] + dpv[q] * wih2[0][s];
          const float gf = acc[1][s][q] + biasv[1][s] + dpv[q] * wih2[1][s];
          const float gg = acc[2][s][q] + biasv[2][s] + dpv[q] * wih2[2][s];
          const float go = acc[3][s][q] + biasv[3][s] + dpv[q] * wih2[3][s];
          float cv = (s == 0) ? c_reg0[q] : c_reg1[q];
          cv = fsig(gf) * cv + fsig(gi) * ftanh(gg);
          const float hv = fsig(go) * ftanh(cv);
          if (s == 0) c_reg0[q] = cv; else c_reg1[q] = cv;
          const int r = (q & 3) + ((q >> 2) << 3) + (half << 2);
          *(unsigned short*)((char*)hA + (r << 10) + (colb ^ (r << 4))) = f2bf(hv);
        }
      }
    }
    __syncthreads();  // B3: hA ready for next step
  }
}

extern "C" void kernel_launch(void* const* d_in, const int* in_sizes, int n_in,
                              void* d_out, int out_size, void* d_ws, size_t ws_size,
                              hipStream_t stream) {
  const float* noise   = (const float*)d_in[0];
  const float* cluster = (const float*)d_in[1];
  const float* gap     = (const float*)d_in[2];
  const float* Wih     = (const float*)d_in[3];
  const float* Whh     = (const float*)d_in[4];
  const float* bih     = (const float*)d_in[5];
  const float* bhh     = (const float*)d_in[6];
  const float* W1      = (const float*)d_in[7];
  const float* b1      = (const float*)d_in[8];
  const float* W2      = (const float*)d_in[9];
  const float* b2      = (const float*)d_in[10];

  unsigned short* us = (unsigned short*)d_ws;  // 1,515,520 shorts = 3.03 MB

  prep_pack<<<(STREAM_SHORTS / 8 + 255) / 256, 256, 0, stream>>>(Wih, Whh, W1, us);
  lstm_seq<<<NBLK, NTHREADS, 0, stream>>>(noise, cluster, gap, Wih, bih, bhh, b1, W2, b2,
                                          us, (float*)d_out);
}